// Round 1
// baseline (69.323 us; speedup 1.0000x reference)
//
#include <hip/hip_runtime.h>
#include <hip/hip_bf16.h>
#include <math.h>

// ROI pooling, faithful to the reference's quirky math:
//   cl = h/n steps along x (width/cc axis), rl = w/n steps along y (height/rr axis)
//   x1[i] = rne_round(x + i*cl), x2[i] = rne_round((x + i*cl) + cl)
//   y1[j] = rne_round(y + j*rl), y2[j] = rne_round((y + j*rl) + rl)
//   pooled[r, i, j, c] = max over rr in [y1,y2)∩[0,H), cc in [x1,x2)∩[0,W) of feat[rr,cc,c]
// Output layout: [R, 21, C] with bins concatenated per level (n=1:0, n=2:1..4, n=4:5..20),
// within a level bin index = i*n + j (ix outer, jy inner).

#define H 56
#define W 56
#define C 256
#define NBINS 21  // 1 + 4 + 16

__global__ __launch_bounds__(256) void roi_pool_kernel(
    const float* __restrict__ feat,   // [H, W, C]
    const float* __restrict__ rois,   // [R, 4] (x, y, w, h)
    float* __restrict__ out)          // [R, NBINS, C]
{
    const int bidx = blockIdx.x;
    const int r    = bidx / NBINS;
    const int bin  = bidx % NBINS;
    const int c    = threadIdx.x;

    const float x = rois[r * 4 + 0];
    const float y = rois[r * 4 + 1];
    const float w = rois[r * 4 + 2];
    const float h = rois[r * 4 + 3];

    int n, i, j;
    if (bin == 0)      { n = 1; i = 0; j = 0; }
    else if (bin < 5)  { n = 2; int b = bin - 1; i = b >> 1; j = b & 1; }
    else               { n = 4; int b = bin - 5; i = b >> 2; j = b & 3; }

    // Exact f32 ops (no FMA contraction) to match the numpy/JAX reference
    // bit-for-bit at round-to-nearest-even boundaries.
    const float cl = __fdiv_rn(h, (float)n);   // step along x (width)
    const float rl = __fdiv_rn(w, (float)n);   // step along y (height)

    const float ax = __fadd_rn(x, __fmul_rn((float)i, cl));
    const int   x1 = (int)rintf(ax);
    const int   x2 = (int)rintf(__fadd_rn(ax, cl));

    const float ay = __fadd_rn(y, __fmul_rn((float)j, rl));
    const int   y1 = (int)rintf(ay);
    const int   y2 = (int)rintf(__fadd_rn(ay, rl));

    const int r0 = max(y1, 0), r1 = min(y2, H);
    const int c0 = max(x1, 0), c1 = min(x2, W);

    float m = -INFINITY;
    for (int rr = r0; rr < r1; ++rr) {
        const float* rowp = feat + ((size_t)rr * W) * C + c;
        for (int cc = c0; cc < c1; ++cc) {
            m = fmaxf(m, rowp[(size_t)cc * C]);
        }
    }

    out[((size_t)r * NBINS + bin) * C + c] = m;
}

extern "C" void kernel_launch(void* const* d_in, const int* in_sizes, int n_in,
                              void* d_out, int out_size, void* d_ws, size_t ws_size,
                              hipStream_t stream) {
    const float* img  = (const float*)d_in[0];   // [1, 56, 56, 256]
    const float* rois = (const float*)d_in[1];   // [1, 32, 4]
    float* out = (float*)d_out;                  // [1, 32, 21*256]

    const int R = in_sizes[1] / 4;               // 32
    dim3 grid(R * NBINS);
    dim3 block(256);
    roi_pool_kernel<<<grid, block, 0, stream>>>(img, rois, out);
}

// Round 2
// 24.779 us; speedup vs baseline: 2.7977x; 2.7977x over previous
//
#include <hip/hip_runtime.h>
#include <hip/hip_bf16.h>
#include <math.h>

// ROI pooling, faithful to the reference's quirky math:
//   cl = h/n steps along x (width/cc axis), rl = w/n steps along y (height/rr axis)
//   x1[i] = rne(x + i*cl), x2[i] = rne((x + i*cl) + cl)
//   y1[j] = rne(y + j*rl), y2[j] = rne((y + j*rl) + rl)
//   pooled[r, i, j, c] = max over rr in [y1,y2)∩[0,H), cc in [x1,x2)∩[0,W)
// Output: [R, 21, C]; levels n=1 (bin 0), n=2 (bins 1..4), n=4 (bins 5..20),
// within a level bin = i*n + j (ix outer, jy inner).
//
// Round 1 -> 2: latency-bound fix. float4 channel-quads (64 lanes x 16B = 1KiB/wave),
// 4 waves split the bin's cells round-robin, x4 unroll with independent accumulators,
// LDS cross-wave max at the end. ~16 loads in flight vs ~1 before.

#define HH 56
#define WW 56
#define NBINS 21  // 1 + 4 + 16

__device__ __forceinline__ float4 fmax4(float4 a, float4 b) {
    float4 r;
    r.x = fmaxf(a.x, b.x);
    r.y = fmaxf(a.y, b.y);
    r.z = fmaxf(a.z, b.z);
    r.w = fmaxf(a.w, b.w);
    return r;
}

__global__ __launch_bounds__(256) void roi_pool_kernel(
    const float4* __restrict__ feat4,  // [H, W, C/4] as float4, idx = (rr*W+cc)*64 + l
    const float* __restrict__ rois,    // [R, 4] (x, y, w, h)
    float4* __restrict__ out4)         // [R, NBINS, C/4]
{
    const int bidx = blockIdx.x;
    const int r    = bidx / NBINS;
    const int bin  = bidx % NBINS;
    const int l    = threadIdx.x & 63;   // channel quad: channels 4l..4l+3
    const int s    = threadIdx.x >> 6;   // wave slice 0..3

    const float x = rois[r * 4 + 0];
    const float y = rois[r * 4 + 1];
    const float w = rois[r * 4 + 2];
    const float h = rois[r * 4 + 3];

    int n, i, j;
    if (bin == 0)      { n = 1; i = 0; j = 0; }
    else if (bin < 5)  { n = 2; int b = bin - 1; i = b >> 1; j = b & 1; }
    else               { n = 4; int b = bin - 5; i = b >> 2; j = b & 3; }

    // Exact f32 ops (no FMA contraction) to match the numpy/JAX reference
    // bit-for-bit at round-to-nearest-even boundaries.
    const float cl = __fdiv_rn(h, (float)n);   // step along x (width)
    const float rl = __fdiv_rn(w, (float)n);   // step along y (height)

    const float ax = __fadd_rn(x, __fmul_rn((float)i, cl));
    const int   x1 = (int)rintf(ax);
    const int   x2 = (int)rintf(__fadd_rn(ax, cl));

    const float ay = __fadd_rn(y, __fmul_rn((float)j, rl));
    const int   y1 = (int)rintf(ay);
    const int   y2 = (int)rintf(__fadd_rn(ay, rl));

    const int r0 = max(y1, 0), r1 = min(y2, HH);
    const int c0 = max(x1, 0), c1 = min(x2, WW);

    const int nr = r1 - r0;
    const int nc = c1 - c0;
    const int ncells = (nr > 0 && nc > 0) ? nr * nc : 0;

    const float4 NEG = make_float4(-INFINITY, -INFINITY, -INFINITY, -INFINITY);
    float4 m0 = NEG, m1 = NEG, m2 = NEG, m3 = NEG;

    const float4* base = feat4 + l;

    int t = s;
    // Unrolled by 4 (stride 16 across the 4 wave-slices): 4 independent loads
    // in flight per thread, 4 independent fmax chains.
    for (; t + 12 < ncells; t += 16) {
        const int t0 = t, t1 = t + 4, t2 = t + 8, t3 = t + 12;
        const int rr0 = r0 + t0 / nc, cc0 = c0 + t0 % nc;
        const int rr1 = r0 + t1 / nc, cc1 = c0 + t1 % nc;
        const int rr2 = r0 + t2 / nc, cc2 = c0 + t2 % nc;
        const int rr3 = r0 + t3 / nc, cc3 = c0 + t3 % nc;
        const float4 v0 = base[((size_t)rr0 * WW + cc0) * 64];
        const float4 v1 = base[((size_t)rr1 * WW + cc1) * 64];
        const float4 v2 = base[((size_t)rr2 * WW + cc2) * 64];
        const float4 v3 = base[((size_t)rr3 * WW + cc3) * 64];
        m0 = fmax4(m0, v0);
        m1 = fmax4(m1, v1);
        m2 = fmax4(m2, v2);
        m3 = fmax4(m3, v3);
    }
    for (; t < ncells; t += 4) {
        const int rr = r0 + t / nc, cc = c0 + t % nc;
        m0 = fmax4(m0, base[((size_t)rr * WW + cc) * 64]);
    }

    float4 m = fmax4(fmax4(m0, m1), fmax4(m2, m3));

    __shared__ float4 buf[4][64];
    buf[s][l] = m;
    __syncthreads();
    if (s == 0) {
        float4 a = fmax4(fmax4(buf[0][l], buf[1][l]),
                         fmax4(buf[2][l], buf[3][l]));
        out4[((size_t)r * NBINS + bin) * 64 + l] = a;
    }
}

extern "C" void kernel_launch(void* const* d_in, const int* in_sizes, int n_in,
                              void* d_out, int out_size, void* d_ws, size_t ws_size,
                              hipStream_t stream) {
    const float4* img  = (const float4*)d_in[0];  // [1, 56, 56, 256] f32
    const float*  rois = (const float*)d_in[1];   // [1, 32, 4]
    float4* out = (float4*)d_out;                 // [1, 32, 21*256]

    const int R = in_sizes[1] / 4;                // 32
    dim3 grid(R * NBINS);
    dim3 block(256);
    roi_pool_kernel<<<grid, block, 0, stream>>>(img, rois, out);
}

// Round 3
// 11.906 us; speedup vs baseline: 5.8225x; 2.0812x over previous
//
#include <hip/hip_runtime.h>
#include <hip/hip_bf16.h>
#include <math.h>

// ROI pooling, faithful to the reference's quirky math:
//   cl = h/n steps along x (width/cc axis), rl = w/n steps along y (height/rr axis)
//   x1[i] = rne(x + i*cl), x2[i] = rne((x + i*cl) + cl)
//   y1[j] = rne(y + j*rl), y2[j] = rne((y + j*rl) + rl)
//   pooled[r, i, j, c] = max over rr in [y1,y2)∩[0,H), cc in [x1,x2)∩[0,W)
// Output: [R, 21, C]; n=1 -> bin 0, n=2 -> bins 1..4, n=4 -> bins 5..20,
// within a level bin = i*n + j (ix outer, jy inner).
//
// Round 2 -> 3: (a) kill integer div/mod in the inner loop (no HW idiv on
// gfx950; was ~30 VALU ops per cell) by walking rows with a stride instead of
// flattened-cell decode; (b) balance: split each level into equal row-tasks:
//   task 0..15  : n=4 bin b (final result -> out directly)
//   task 16..23 : n=2 bin b=(t-16)>>1, row-part p=(t-16)&1  -> ws slot 0..7
//   task 24..31 : n=1, row-part p=t-24 (8 parts)            -> ws slot 8..15
// Worst task ~113 cells (~28 loads/thread) vs 900 cells in one block before.
// Kernel B (32 blocks x 1 wave) max-combines ws partials into bins 0..4.
// Boundary math is evaluated per-task exactly as the reference does it (no
// cross-level tiling assumption: (x+i*cl)+cl is double-rounded and need not
// bitwise-equal x+(i+1)*cl).

#define HH 56
#define WW 56
#define NBINS 21  // 1 + 4 + 16

__device__ __forceinline__ float4 fmax4(float4 a, float4 b) {
    float4 r;
    r.x = fmaxf(a.x, b.x);
    r.y = fmaxf(a.y, b.y);
    r.z = fmaxf(a.z, b.z);
    r.w = fmaxf(a.w, b.w);
    return r;
}

__global__ __launch_bounds__(256) void roi_pool_partial(
    const float4* __restrict__ feat4,  // [56,56,64] float4
    const float* __restrict__ rois,    // [R,4] (x,y,w,h)
    float4* __restrict__ out4,         // [R,21,64] float4
    float4* __restrict__ ws4)          // [R,16,64] float4 partials
{
    const int bid  = blockIdx.x;
    const int r    = bid >> 5;        // / 32 tasks
    const int task = bid & 31;
    const int l    = threadIdx.x & 63;   // channel quad (channels 4l..4l+3)
    const int s    = threadIdx.x >> 6;   // wave slice 0..3

    const float x = rois[r * 4 + 0];
    const float y = rois[r * 4 + 1];
    const float w = rois[r * 4 + 2];
    const float h = rois[r * 4 + 3];

    int n, i, j, row_off, row_stride;
    if (task < 16) {            // n=4 bins: <=9 rows, stride 4 over slices
        n = 4; i = task >> 2; j = task & 3;
        row_off = s; row_stride = 4;
    } else if (task < 24) {     // n=2 bins, 2 row-parts: <=16 rows, stride 8
        n = 2;
        const int b = (task - 16) >> 1, p = (task - 16) & 1;
        i = b >> 1; j = b & 1;
        row_off = p * 4 + s; row_stride = 8;
    } else {                    // n=1, 8 row-parts: <=31 rows, stride 32
        n = 1; i = 0; j = 0;
        const int p = task - 24;
        row_off = p + s * 8; row_stride = 32;
    }

    // Exact f32 ops (no FMA contraction) to match the numpy/JAX reference
    // bit-for-bit at round-to-nearest-even boundaries.
    const float cl = __fdiv_rn(h, (float)n);   // step along x (width)
    const float rl = __fdiv_rn(w, (float)n);   // step along y (height)

    const float ax = __fadd_rn(x, __fmul_rn((float)i, cl));
    const int   x1 = (int)rintf(ax);
    const int   x2 = (int)rintf(__fadd_rn(ax, cl));

    const float ay = __fadd_rn(y, __fmul_rn((float)j, rl));
    const int   y1 = (int)rintf(ay);
    const int   y2 = (int)rintf(__fadd_rn(ay, rl));

    const int r0 = max(y1, 0), r1 = min(y2, HH);
    const int c0 = max(x1, 0), c1 = min(x2, WW);

    const float4 NEG = make_float4(-INFINITY, -INFINITY, -INFINITY, -INFINITY);
    float4 m0 = NEG, m1 = NEG, m2 = NEG, m3 = NEG;

    const float4* basel = feat4 + l;
    for (int rr = r0 + row_off; rr < r1; rr += row_stride) {
        const float4* rowp = basel + (size_t)(rr * WW) * 64;
        int cc = c0;
        for (; cc + 4 <= c1; cc += 4) {   // 4 independent chains / 4 loads in flight
            m0 = fmax4(m0, rowp[(size_t)(cc)     * 64]);
            m1 = fmax4(m1, rowp[(size_t)(cc + 1) * 64]);
            m2 = fmax4(m2, rowp[(size_t)(cc + 2) * 64]);
            m3 = fmax4(m3, rowp[(size_t)(cc + 3) * 64]);
        }
        for (; cc < c1; ++cc)
            m0 = fmax4(m0, rowp[(size_t)cc * 64]);
    }
    float4 m = fmax4(fmax4(m0, m1), fmax4(m2, m3));

    __shared__ float4 buf[4][64];
    buf[s][l] = m;
    __syncthreads();
    if (s == 0) {
        float4 a = fmax4(fmax4(buf[0][l], buf[1][l]),
                         fmax4(buf[2][l], buf[3][l]));
        if (task < 16)
            out4[((size_t)r * NBINS + 5 + task) * 64 + l] = a;      // n=4 final
        else
            ws4[((size_t)r * 16 + (task - 16)) * 64 + l] = a;       // partial
    }
}

__global__ __launch_bounds__(64) void roi_pool_combine(
    const float4* __restrict__ ws4,    // [R,16,64]: slots 0..7 n=2 halves, 8..15 n=1 parts
    float4* __restrict__ out4)         // [R,21,64]
{
    const int r = blockIdx.x;
    const int l = threadIdx.x;         // 0..63
    const float4* wsr = ws4 + (size_t)r * 16 * 64 + l;

    // n=2 bins (out bins 1..4): combine the two row-halves
    #pragma unroll
    for (int b = 0; b < 4; ++b) {
        float4 a = fmax4(wsr[(size_t)(2 * b) * 64], wsr[(size_t)(2 * b + 1) * 64]);
        out4[((size_t)r * NBINS + 1 + b) * 64 + l] = a;
    }

    // n=1 bin (out bin 0): combine the 8 row-parts
    float4 a0 = fmax4(wsr[(size_t)8 * 64],  wsr[(size_t)9 * 64]);
    float4 a1 = fmax4(wsr[(size_t)10 * 64], wsr[(size_t)11 * 64]);
    float4 a2 = fmax4(wsr[(size_t)12 * 64], wsr[(size_t)13 * 64]);
    float4 a3 = fmax4(wsr[(size_t)14 * 64], wsr[(size_t)15 * 64]);
    float4 a  = fmax4(fmax4(a0, a1), fmax4(a2, a3));
    out4[((size_t)r * NBINS + 0) * 64 + l] = a;
}

extern "C" void kernel_launch(void* const* d_in, const int* in_sizes, int n_in,
                              void* d_out, int out_size, void* d_ws, size_t ws_size,
                              hipStream_t stream) {
    const float4* img  = (const float4*)d_in[0];  // [1,56,56,256] f32
    const float*  rois = (const float*)d_in[1];   // [1,32,4]
    float4* out = (float4*)d_out;                 // [1,32,21*256]
    float4* ws  = (float4*)d_ws;                  // >= R*16*256*4 B = 512 KB

    const int R = in_sizes[1] / 4;                // 32

    roi_pool_partial<<<dim3(R * 32), dim3(256), 0, stream>>>(img, rois, out, ws);
    roi_pool_combine<<<dim3(R), dim3(64), 0, stream>>>(ws, out);
}

// Round 4
// 10.726 us; speedup vs baseline: 6.4633x; 1.1101x over previous
//
#include <hip/hip_runtime.h>
#include <hip/hip_bf16.h>
#include <math.h>

// ROI pooling, faithful to the reference's quirky math:
//   cl = h/n steps along x (width/cc axis), rl = w/n steps along y (height/rr axis)
//   x1[i] = rne(x + i*cl), x2[i] = rne((x + i*cl) + cl)
//   y1[j] = rne(y + j*rl), y2[j] = rne((y + j*rl) + rl)
//   pooled[r, i, j, c] = max over rr in [y1,y2)∩[0,H), cc in [x1,x2)∩[0,W)
// Output: [R, 21, C]; n=1 -> bin 0, n=2 -> bins 1..4, n=4 -> bins 5..20,
// within a level bin = i*n + j (ix outer, jy inner).
//
// Round 3 -> 4: ONE kernel (saves a ~5us launch), every bin block-local:
//   task 0..3 : n=1 bin, channel group task (64 ch), 64 cell-slices (8x8)
//   task 4..7 : n=2 bin task-4, all 256 ch, 16 cell-slices (4x4)
//   task 8..15: n=4 bins {2k, 2k+1}, half-block each, 8 slices (2x4)
// Every thread: <=4 rows x <=4 peeled col-slots = <=16 loads, no div/mod,
// no dynamic-index accumulators. Reduce: __shfl_xor in-wave + LDS tree.
// Grid = 32 ROIs x 16 tasks = 512 blocks x 16 waves = 8192 waves (= capacity).

#define HH 56
#define WW 56
#define NBINS 21  // 1 + 4 + 16

__device__ __forceinline__ float4 fmax4(float4 a, float4 b) {
    float4 r;
    r.x = fmaxf(a.x, b.x);
    r.y = fmaxf(a.y, b.y);
    r.z = fmaxf(a.z, b.z);
    r.w = fmaxf(a.w, b.w);
    return r;
}

__device__ __forceinline__ float4 shflxor4(float4 v, int mask) {
    float4 r;
    r.x = __shfl_xor(v.x, mask);
    r.y = __shfl_xor(v.y, mask);
    r.z = __shfl_xor(v.z, mask);
    r.w = __shfl_xor(v.w, mask);
    return r;
}

__global__ __launch_bounds__(1024, 8) void roi_pool_fused(
    const float4* __restrict__ feat4,  // [56,56,64] float4
    const float* __restrict__ rois,    // [R,4] (x,y,w,h)
    float4* __restrict__ out4)         // [R,21,64] float4
{
    const int bid  = blockIdx.x;
    const int r    = bid >> 4;
    const int task = bid & 15;
    const int t    = threadIdx.x;

    const float x = rois[r * 4 + 0];
    const float y = rois[r * 4 + 1];
    const float w = rois[r * 4 + 2];
    const float h = rois[r * 4 + 3];

    int n, i, j, q, sr, sc, rstr, cstr;
    if (task < 4) {            // n=1, channel-split: 16 quads, 64 slices (8x8)
        n = 1; i = 0; j = 0;
        q = (task << 4) | (t & 15);
        const int s = t >> 4;          // 0..63
        sr = s & 7;  sc = s >> 3;  rstr = 8; cstr = 8;
    } else if (task < 8) {     // n=2 bin: 64 quads, 16 slices (4x4)
        n = 2;
        const int b = task - 4; i = b >> 1; j = b & 1;
        q = t & 63;
        const int s = t >> 6;          // 0..15
        sr = s & 3;  sc = s >> 2;  rstr = 4; cstr = 4;
    } else {                   // n=4, two bins per block, 8 slices each (2x4)
        n = 4;
        const int s = t >> 6;          // 0..15
        const int b = ((task - 8) << 1) | (s >> 3);   // bin 0..15
        i = b >> 2; j = b & 3;
        q = t & 63;
        const int sh = s & 7;
        sr = sh & 1; sc = sh >> 1; rstr = 2; cstr = 4;
    }

    // Exact f32 ops (no FMA contraction) to match the numpy/JAX reference
    // bit-for-bit at round-to-nearest-even boundaries.
    const float cl = __fdiv_rn(h, (float)n);   // step along x (width)
    const float rl = __fdiv_rn(w, (float)n);   // step along y (height)

    const float ax = __fadd_rn(x, __fmul_rn((float)i, cl));
    const int   x1 = (int)rintf(ax);
    const int   x2 = (int)rintf(__fadd_rn(ax, cl));

    const float ay = __fadd_rn(y, __fmul_rn((float)j, rl));
    const int   y1 = (int)rintf(ay);
    const int   y2 = (int)rintf(__fadd_rn(ay, rl));

    const int r0 = max(y1, 0), r1 = min(y2, HH);
    const int c0 = max(x1, 0), c1 = min(x2, WW);

    const float4 NEG = make_float4(-INFINITY, -INFINITY, -INFINITY, -INFINITY);
    float4 m0 = NEG, m1 = NEG, m2 = NEG, m3 = NEG;

    const float4* basel = feat4 + q;
    const int cc0 = c0 + sc;
    const int cc1 = cc0 + cstr;
    const int cc2 = cc1 + cstr;
    const int cc3 = cc2 + cstr;
    // Loop-invariant col guards (hoisted by the compiler); rows <=4 iters.
    for (int rr = r0 + sr; rr < r1; rr += rstr) {
        const float4* rowp = basel + (size_t)(rr * WW) * 64;
        if (cc0 < c1) {
            m0 = fmax4(m0, rowp[(size_t)cc0 * 64]);
            if (cc1 < c1) {
                m1 = fmax4(m1, rowp[(size_t)cc1 * 64]);
                if (cc2 < c1) {
                    m2 = fmax4(m2, rowp[(size_t)cc2 * 64]);
                    if (cc3 < c1) {
                        m3 = fmax4(m3, rowp[(size_t)cc3 * 64]);
                    }
                }
            }
        }
    }
    float4 m = fmax4(fmax4(m0, m1), fmax4(m2, m3));

    __shared__ float4 buf[16][64];  // 16 KB
    const int lane = t & 63;
    const int wv   = t >> 6;

    if (task < 4) {
        // in-wave: each wave holds 4 slices (lane>>4) x 16 quads (lane&15)
        m = fmax4(m, shflxor4(m, 16));
        m = fmax4(m, shflxor4(m, 32));
        if (lane < 16) buf[wv][lane] = m;     // [wave][quad]
        __syncthreads();
        if (t < 64) {
            const int p  = lane >> 4;          // 0..3
            const int ql = lane & 15;
            float4 v = fmax4(fmax4(buf[p][ql], buf[p + 4][ql]),
                             fmax4(buf[p + 8][ql], buf[p + 12][ql]));
            v = fmax4(v, shflxor4(v, 16));
            v = fmax4(v, shflxor4(v, 32));
            if (t < 16)
                out4[((size_t)r * NBINS + 0) * 64 + (task << 4) + t] = v;
        }
    } else if (task < 8) {
        buf[wv][lane] = m;
        __syncthreads();
        if (wv < 4) {
            float4 v = fmax4(fmax4(buf[wv][lane], buf[wv + 4][lane]),
                             fmax4(buf[wv + 8][lane], buf[wv + 12][lane]));
            buf[wv][lane] = v;
        }
        __syncthreads();
        if (wv == 0) {
            float4 v = fmax4(fmax4(buf[0][lane], buf[1][lane]),
                             fmax4(buf[2][lane], buf[3][lane]));
            const int bin = 1 + (task - 4);
            out4[((size_t)r * NBINS + bin) * 64 + lane] = v;
        }
    } else {
        buf[wv][lane] = m;
        __syncthreads();
        const int half = wv >> 3;
        const int p    = wv & 7;
        if (p < 2) {
            const int base = (half << 3) + p;
            float4 v = fmax4(fmax4(buf[base][lane], buf[base + 2][lane]),
                             fmax4(buf[base + 4][lane], buf[base + 6][lane]));
            buf[base][lane] = v;
        }
        __syncthreads();
        if (p == 0) {
            const int base = half << 3;
            float4 v = fmax4(buf[base][lane], buf[base + 1][lane]);
            const int b = ((task - 8) << 1) | half;   // bin 0..15
            out4[((size_t)r * NBINS + 5 + b) * 64 + lane] = v;
        }
    }
}

extern "C" void kernel_launch(void* const* d_in, const int* in_sizes, int n_in,
                              void* d_out, int out_size, void* d_ws, size_t ws_size,
                              hipStream_t stream) {
    const float4* img  = (const float4*)d_in[0];  // [1,56,56,256] f32
    const float*  rois = (const float*)d_in[1];   // [1,32,4]
    float4* out = (float4*)d_out;                 // [1,32,21*256]

    const int R = in_sizes[1] / 4;                // 32

    roi_pool_fused<<<dim3(R * 16), dim3(1024), 0, stream>>>(img, rois, out);
}